// Round 2
// baseline (3358.402 us; speedup 1.0000x reference)
//
#include <hip/hip_runtime.h>

typedef float f4 __attribute__((ext_vector_type(4)));
typedef float f2 __attribute__((ext_vector_type(2)));

#define N_ROWS  32768
#define D_DIM   256
#define K_CODES 8192
#define TM      64          // rows per block (sieve)
#define TK      256         // codes per tile (sieve)
#define NUM_ELEM (N_ROWS * D_DIM)   // 8388608
#define EPS_MARGIN 2e-3f    // > 7x worst-case |dist32 - dist64| bound (~2.7e-4)
#define FB_CAP  8192        // flagged-row list capacity
#define FB_RPB  8           // flagged rows per refine block

// -------- ee[k] = sum_d E[d][k]^2 (fp64 accumulate, round once) --------
__global__ void ee_kernel(const float* __restrict__ E, float* __restrict__ ee) {
    const int k = blockIdx.x * blockDim.x + threadIdx.x;
    double s = 0.0;
    for (int d = 0; d < D_DIM; ++d) {
        float v = E[(size_t)d * K_CODES + k];
        s += (double)v * (double)v;
    }
    ee[k] = (float)s;
}

// -------- fp32 sieve: dist/argmin(top-2)/gather/ST-output/loss --------
__launch_bounds__(256, 2)
__global__ void vq_kernel(const float* __restrict__ X, const float* __restrict__ E,
                          const float* __restrict__ ee, float* __restrict__ out,
                          double* __restrict__ loss_sum, int* __restrict__ counter,
                          int2* __restrict__ list) {
    __shared__ __align__(16) float xs[TM * D_DIM];   // 64 KB, XOR-swizzled granules
    const int t    = threadIdx.x;
    const int row0 = blockIdx.x * TM;
    const int tr   = t >> 4;
    const int tc   = t & 15;
    const int sw   = tr & 7;

    #pragma unroll
    for (int c = 0; c < 16; ++c) {
        int flat = c * 1024 + t * 4;
        int r = flat >> 8;
        int d = flat & 255;
        int g = (d >> 2) ^ ((r >> 2) & 7);
        f4 v = *(const f4*)(X + (size_t)(row0 + r) * D_DIM + d);
        *(f4*)(xs + r * D_DIM + (g << 2)) = v;
    }

    float xxr[4];
    #pragma unroll
    for (int i = 0; i < 4; ++i) {
        const f4* xp = (const f4*)(X + (size_t)(row0 + tr * 4 + i) * D_DIM);
        double s = 0.0;
        for (int d4 = 0; d4 < 64; ++d4) {
            f4 v = xp[d4];
            s += (double)v[0] * v[0]; s += (double)v[1] * v[1];
            s += (double)v[2] * v[2]; s += (double)v[3] * v[3];
        }
        xxr[i] = (float)s;
    }
    __syncthreads();

    float bestv[4], secv[4];
    int   besti[4];
    #pragma unroll
    for (int i = 0; i < 4; ++i) { bestv[i] = 1e30f; secv[i] = 1e30f; besti[i] = 0; }

    for (int kt = 0; kt < K_CODES; kt += TK) {
        float acc[4][16];
        #pragma unroll
        for (int i = 0; i < 4; ++i)
            #pragma unroll
            for (int q = 0; q < 16; ++q) acc[i][q] = 0.0f;

        const float* Eb = E + kt + tc * 4;

        for (int dd4 = 0; dd4 < 64; ++dd4) {
            f4 xv[4];
            const float* xrow = xs + ((dd4 ^ sw) << 2);
            #pragma unroll
            for (int i = 0; i < 4; ++i)
                xv[i] = *(const f4*)(xrow + (tr * 4 + i) * D_DIM);

            #pragma unroll
            for (int j = 0; j < 4; ++j) {
                const float* Er = Eb + (size_t)(dd4 * 4 + j) * K_CODES;
                f4 em[4];
                #pragma unroll
                for (int m = 0; m < 4; ++m)
                    em[m] = *(const f4*)(Er + (m << 6));
                #pragma unroll
                for (int i = 0; i < 4; ++i) {
                    float xj = xv[i][j];
                    #pragma unroll
                    for (int m = 0; m < 4; ++m) {
                        #pragma unroll
                        for (int cc = 0; cc < 4; ++cc)
                            acc[i][m * 4 + cc] += xj * em[m][cc];
                    }
                }
            }
        }

        f4 eev[4];
        #pragma unroll
        for (int m = 0; m < 4; ++m)
            eev[m] = *(const f4*)(ee + kt + (m << 6) + tc * 4);
        #pragma unroll
        for (int i = 0; i < 4; ++i) {
            #pragma unroll
            for (int m = 0; m < 4; ++m) {
                #pragma unroll
                for (int cc = 0; cc < 4; ++cc) {
                    float dist = (xxr[i] - 2.0f * acc[i][m * 4 + cc]) + eev[m][cc];
                    int code = kt + (m << 6) + tc * 4 + cc;
                    if (dist < bestv[i]) { secv[i] = bestv[i]; bestv[i] = dist; besti[i] = code; }
                    else if (dist < secv[i]) { secv[i] = dist; }
                }
            }
        }
    }

    // top-2 merge across the 16 tc lanes
    #pragma unroll
    for (int off = 1; off < 16; off <<= 1) {
        #pragma unroll
        for (int i = 0; i < 4; ++i) {
            float ov = __shfl_xor(bestv[i], off);
            int   oi = __shfl_xor(besti[i], off);
            float os = __shfl_xor(secv[i], off);
            bool owin = (ov < bestv[i]) || (ov == bestv[i] && oi < besti[i]);
            if (owin) { secv[i] = fminf(os, bestv[i]); bestv[i] = ov; besti[i] = oi; }
            else      { secv[i] = fminf(secv[i], ov); }
        }
    }

    __syncthreads();
    int* bidx = (int*)xs;
    if (tc == 0) {
        #pragma unroll
        for (int i = 0; i < 4; ++i) {
            bidx[tr * 4 + i] = besti[i];
            if (secv[i] - bestv[i] <= EPS_MARGIN) {   // fp64 argmin not provable -> flag
                int pos = atomicAdd(counter, 1);
                if (pos < FB_CAP) list[pos] = make_int2(row0 + tr * 4 + i, besti[i]);
            }
        }
    }
    __syncthreads();

    double ls = 0.0;
    const int d = t;
    #pragma unroll 4
    for (int r = 0; r < TM; ++r) {
        int code = bidx[r];
        float q  = E[(size_t)d * K_CODES + code];
        float x  = X[(size_t)(row0 + r) * D_DIM + d];
        float dq = q - x;
        out[(size_t)(row0 + r) * D_DIM + d] = x + dq;
        ls += (double)dq * (double)dq;
    }
    #pragma unroll
    for (int off = 32; off > 0; off >>= 1)
        ls += __shfl_down(ls, off);
    if ((t & 63) == 0) atomicAdd(loss_sum, ls);
}

// -------- fp64 exact re-argmin for flagged rows; patch out + loss --------
__global__ void refine_kernel(const float* __restrict__ X, const float* __restrict__ E,
                              float* __restrict__ out, double* __restrict__ loss_sum,
                              const int* __restrict__ counter, const int2* __restrict__ list) {
    __shared__ float xt[D_DIM][FB_RPB];       // x transposed [d][j], 8 KB
    __shared__ int rows_sh[FB_RPB], old_sh[FB_RPB], act_sh[FB_RPB], win_sh[FB_RPB];
    __shared__ double wbv[4][FB_RPB];
    __shared__ int    wbi[4][FB_RPB];

    int n = *counter; if (n > FB_CAP) n = FB_CAP;
    const int e0 = blockIdx.x * FB_RPB;
    if (e0 >= n) return;
    const int t = threadIdx.x;

    if (t < FB_RPB) {
        int e = e0 + t;
        int a = (e < n) ? 1 : 0;
        int2 ent = list[a ? e : e0];
        rows_sh[t] = ent.x; old_sh[t] = ent.y; act_sh[t] = a;
    }
    __syncthreads();
    #pragma unroll
    for (int j = 0; j < FB_RPB; ++j)
        xt[t][j] = X[(size_t)rows_sh[j] * D_DIM + t];
    __syncthreads();

    double bv[FB_RPB]; int bi[FB_RPB];
    #pragma unroll
    for (int j = 0; j < FB_RPB; ++j) { bv[j] = 1e300; bi[j] = 0; }

    for (int kt = 0; kt < 16; ++kt) {
        const int k0 = kt * 512 + t * 2;
        double s0[FB_RPB], s1[FB_RPB], q0 = 0.0, q1 = 0.0;
        #pragma unroll
        for (int j = 0; j < FB_RPB; ++j) { s0[j] = 0.0; s1[j] = 0.0; }

        for (int d = 0; d < D_DIM; ++d) {
            f2 ev = *(const f2*)(E + (size_t)d * K_CODES + k0);
            double e0d = (double)ev[0], e1d = (double)ev[1];
            const f4* xp = (const f4*)(&xt[d][0]);
            f4 xa = xp[0], xb = xp[1];           // broadcast LDS reads
            double xd[FB_RPB] = { (double)xa[0], (double)xa[1], (double)xa[2], (double)xa[3],
                                  (double)xb[0], (double)xb[1], (double)xb[2], (double)xb[3] };
            q0 += e0d * e0d; q1 += e1d * e1d;
            #pragma unroll
            for (int j = 0; j < FB_RPB; ++j) {
                s0[j] += xd[j] * e0d;
                s1[j] += xd[j] * e1d;
            }
        }
        #pragma unroll
        for (int j = 0; j < FB_RPB; ++j) {
            double k0v = q0 - 2.0 * s0[j];        // ||x||^2 constant: irrelevant for argmin
            double k1v = q1 - 2.0 * s1[j];
            if (k0v < bv[j]) { bv[j] = k0v; bi[j] = k0; }
            if (k1v < bv[j]) { bv[j] = k1v; bi[j] = k0 + 1; }
        }
    }

    // wave reduce (argmin, lowest-index ties)
    #pragma unroll
    for (int off = 1; off < 64; off <<= 1) {
        #pragma unroll
        for (int j = 0; j < FB_RPB; ++j) {
            double ov = __shfl_xor(bv[j], off);
            int    oi = __shfl_xor(bi[j], off);
            if (ov < bv[j] || (ov == bv[j] && oi < bi[j])) { bv[j] = ov; bi[j] = oi; }
        }
    }
    const int wave = t >> 6;
    if ((t & 63) == 0) {
        #pragma unroll
        for (int j = 0; j < FB_RPB; ++j) { wbv[wave][j] = bv[j]; wbi[wave][j] = bi[j]; }
    }
    __syncthreads();
    if (t < FB_RPB) {
        double b = wbv[0][t]; int i_ = wbi[0][t];
        #pragma unroll
        for (int w = 1; w < 4; ++w) {
            double ov = wbv[w][t]; int oi = wbi[w][t];
            if (ov < b || (ov == b && oi < i_)) { b = ov; i_ = oi; }
        }
        win_sh[t] = i_;
    }
    __syncthreads();

    // patch output rows whose code changed; accumulate loss delta
    double dl = 0.0;
    #pragma unroll
    for (int j = 0; j < FB_RPB; ++j) {
        if (!act_sh[j]) continue;                 // block-uniform
        int nc = win_sh[j], oc = old_sh[j];
        if (nc == oc) continue;                   // block-uniform
        int row = rows_sh[j];
        float x  = xt[t][j];
        float qn = E[(size_t)t * K_CODES + nc];
        float qo = E[(size_t)t * K_CODES + oc];
        float dqn = qn - x, dqo = qo - x;
        out[(size_t)row * D_DIM + t] = x + dqn;
        dl += (double)dqn * dqn - (double)dqo * dqo;
    }
    #pragma unroll
    for (int off = 32; off > 0; off >>= 1)
        dl += __shfl_down(dl, off);
    if ((t & 63) == 0 && dl != 0.0) atomicAdd(loss_sum, dl);
}

// -------- finalize loss = 0.25*m + m --------
__global__ void fin_kernel(const double* __restrict__ loss_sum, float* __restrict__ out) {
    double m = loss_sum[0] / (double)NUM_ELEM;
    out[NUM_ELEM] = (float)(0.25 * m + m);
}

extern "C" void kernel_launch(void* const* d_in, const int* in_sizes, int n_in,
                              void* d_out, int out_size, void* d_ws, size_t ws_size,
                              hipStream_t stream) {
    const float* X = (const float*)d_in[0];   // [32,1024,256] fp32
    const float* E = (const float*)d_in[1];   // [256,8192] fp32
    float* out = (float*)d_out;               // 8388608 quantized_st + 1 loss
    double* loss_sum = (double*)d_ws;                       // [0,8)
    int*    counter  = (int*)((char*)d_ws + 8);             // [8,12)
    float*  ee       = (float*)((char*)d_ws + 256);         // 32 KB
    int2*   list     = (int2*)((char*)d_ws + 256 + 32768);  // 64 KB

    hipMemsetAsync(d_ws, 0, 256, stream);     // zero loss accumulator + counter
    ee_kernel<<<K_CODES / 256, 256, 0, stream>>>(E, ee);
    vq_kernel<<<N_ROWS / TM, 256, 0, stream>>>(X, E, ee, out, loss_sum, counter, list);
    refine_kernel<<<FB_CAP / FB_RPB, 256, 0, stream>>>(X, E, out, loss_sum, counter, list);
    fin_kernel<<<1, 1, 0, stream>>>(loss_sum, out);
}

// Round 3
// 2242.467 us; speedup vs baseline: 1.4976x; 1.4976x over previous
//
#include <hip/hip_runtime.h>

typedef float f4   __attribute__((ext_vector_type(4)));
typedef float f2   __attribute__((ext_vector_type(2)));
typedef short bf16x8 __attribute__((ext_vector_type(8)));
typedef float f32x4  __attribute__((ext_vector_type(4)));
typedef unsigned int u32x4 __attribute__((ext_vector_type(4)));

#define N_ROWS  32768
#define D_DIM   256
#define K_CODES 8192
#define NUM_ELEM (N_ROWS * D_DIM)
#define EPS_MARGIN 1e-3f     // > 2.7x the paranoid |key32-key64| bound (~3.7e-4)
#define FB_CAP  8192
#define FB_RPB  8
#define SM_CODES 32          // codes per sieve supertile

__device__ __forceinline__ short f2bf(float f) {   // RNE float->bf16 bits
    union { float f; unsigned u; } v; v.f = f;
    unsigned r = v.u + 0x7FFFu + ((v.u >> 16) & 1u);
    return (short)(r >> 16);
}
__device__ __forceinline__ float bf2f(short h) {
    union { unsigned u; float f; } v; v.u = ((unsigned)(unsigned short)h) << 16;
    return v.f;
}

// -------- ee[k] = sum_d E[d][k]^2 (fp64 accumulate, round once) --------
__global__ void ee_kernel(const float* __restrict__ E, float* __restrict__ ee) {
    const int k = blockIdx.x * blockDim.x + threadIdx.x;
    double s = 0.0;
    for (int d = 0; d < D_DIM; ++d) {
        float v = E[(size_t)d * K_CODES + k];
        s += (double)v * (double)v;
    }
    ee[k] = (float)s;
}

// -------- transpose + bf16 hi/lo split: E[256][8192] -> Eth/Etl[8192][256] --------
__global__ void trans_kernel(const float* __restrict__ E,
                             short* __restrict__ Eth, short* __restrict__ Etl) {
    __shared__ float tile[64][65];
    const int t  = threadIdx.x;          // 256
    const int k0 = blockIdx.x * 64;      // code base
    const int d0 = blockIdx.y * 64;      // dim base
    #pragma unroll
    for (int i = 0; i < 16; ++i) {
        int dd = i * 4 + (t >> 6), kk = t & 63;
        tile[dd][kk] = E[(size_t)(d0 + dd) * K_CODES + k0 + kk];
    }
    __syncthreads();
    #pragma unroll
    for (int i = 0; i < 16; ++i) {
        int kk = i * 4 + (t >> 6), dd = t & 63;
        float x = tile[dd][kk];
        short h = f2bf(x);
        short l = f2bf(x - bf2f(h));
        Eth[(size_t)(k0 + kk) * D_DIM + d0 + dd] = h;
        Etl[(size_t)(k0 + kk) * D_DIM + d0 + dd] = l;
    }
}

// -------- MFMA sieve: bf16-split GEMM + top-2 argmin + gather/out/loss --------
__launch_bounds__(256, 2)
__global__ void mfma_vq_kernel(const float* __restrict__ X, const float* __restrict__ E,
                               const short* __restrict__ Eth, const short* __restrict__ Etl,
                               const float* __restrict__ ee, float* __restrict__ out,
                               double* __restrict__ loss_sum, int* __restrict__ counter,
                               int2* __restrict__ list) {
    // B panel: 32 codes x 256 d, bf16 h+l, 16B granules XOR-swizzled: granule (c,g)
    // lives at c*256 + ((g ^ c)*8) shorts  (g = d-chunk 0..31)
    __shared__ __align__(16) short Bh[SM_CODES * 256];   // 16 KB
    __shared__ __align__(16) short Bl[SM_CODES * 256];   // 16 KB
    __shared__ int bidx[128];

    const int t    = threadIdx.x;
    const int w    = t >> 6;
    const int lane = t & 63;
    const int n    = lane & 15;
    const int quad = lane >> 4;
    const int row0 = blockIdx.x * 128;
    const int rw   = row0 + w * 32;      // this wave's 32 rows

    // ---- A fragments (32 rows x 256 d, h+l) -> registers ----
    // A[m = lane&15][k = quad*8 + j] for mfma_f32_16x16x32_bf16
    bf16x8 Ah[2][8], Al[2][8];
    #pragma unroll
    for (int rt = 0; rt < 2; ++rt) {
        const float* xp = X + (size_t)(rw + rt * 16 + n) * D_DIM;
        #pragma unroll
        for (int ks = 0; ks < 8; ++ks) {
            int d = ks * 32 + quad * 8;
            f4 a = *(const f4*)(xp + d);
            f4 b = *(const f4*)(xp + d + 4);
            bf16x8 h, l;
            #pragma unroll
            for (int j = 0; j < 8; ++j) {
                float x = (j < 4) ? a[j] : b[j - 4];
                short hh = f2bf(x);
                h[j] = hh;
                l[j] = f2bf(x - bf2f(hh));
            }
            Ah[rt][ks] = h; Al[rt][ks] = l;
        }
    }

    // per-lane argmin slots: slot s=rt*4+r -> row rw + rt*16 + quad*4 + r
    float bestv[8], secv[8]; int besti[8];
    #pragma unroll
    for (int s = 0; s < 8; ++s) { bestv[s] = 1e30f; secv[s] = 1e30f; besti[s] = 0; }

    for (int cb = 0; cb < K_CODES; cb += SM_CODES) {
        __syncthreads();                          // prior reads done before overwrite
        {   // stage B panel: thread -> code c=t>>3, half=(t>>2)&1, granules (t&3)*8..+8
            int c = t >> 3;
            const short* src = ((t >> 2) & 1) ? Etl : Eth;
            short* dst       = ((t >> 2) & 1) ? Bl  : Bh;
            int g0 = (t & 3) * 8;
            const short* sp = src + (size_t)(cb + c) * D_DIM + g0 * 8;
            #pragma unroll
            for (int k = 0; k < 8; ++k) {
                u32x4 v = *(const u32x4*)(sp + k * 8);
                int g = (g0 + k) ^ c;
                *(u32x4*)(dst + c * 256 + g * 8) = v;
            }
        }
        __syncthreads();

        f32x4 acc[2][2];                          // [ct][rt]
        #pragma unroll
        for (int ct = 0; ct < 2; ++ct)
            #pragma unroll
            for (int rt = 0; rt < 2; ++rt)
                acc[ct][rt] = (f32x4)(0.0f);

        #pragma unroll
        for (int ks = 0; ks < 8; ++ks) {
            bf16x8 bh[2], bl[2];
            #pragma unroll
            for (int ct = 0; ct < 2; ++ct) {
                int c = ct * 16 + n;
                int g = (ks * 4 + quad) ^ c;
                bh[ct] = *(const bf16x8*)(Bh + c * 256 + g * 8);
                bl[ct] = *(const bf16x8*)(Bl + c * 256 + g * 8);
            }
            #pragma unroll
            for (int ct = 0; ct < 2; ++ct)
                #pragma unroll
                for (int rt = 0; rt < 2; ++rt) {
                    acc[ct][rt] = __builtin_amdgcn_mfma_f32_16x16x32_bf16(Ah[rt][ks], bh[ct], acc[ct][rt], 0, 0, 0);
                    acc[ct][rt] = __builtin_amdgcn_mfma_f32_16x16x32_bf16(Al[rt][ks], bh[ct], acc[ct][rt], 0, 0, 0);
                    acc[ct][rt] = __builtin_amdgcn_mfma_f32_16x16x32_bf16(Ah[rt][ks], bl[ct], acc[ct][rt], 0, 0, 0);
                }
        }

        // epilogue: key = ee - 2*s  (||x||^2 constant dropped; same margins)
        #pragma unroll
        for (int ct = 0; ct < 2; ++ct) {
            int code = cb + ct * 16 + n;
            float eev = ee[code];
            #pragma unroll
            for (int rt = 0; rt < 2; ++rt)
                #pragma unroll
                for (int r = 0; r < 4; ++r) {
                    float key = fmaf(-2.0f, acc[ct][rt][r], eev);
                    int s = rt * 4 + r;
                    if (key < bestv[s]) { secv[s] = bestv[s]; bestv[s] = key; besti[s] = code; }
                    else if (key < secv[s]) { secv[s] = key; }
                }
        }
    }

    // top-2 merge across the 16 'n' lanes (rows identical across them)
    #pragma unroll
    for (int off = 1; off < 16; off <<= 1) {
        #pragma unroll
        for (int s = 0; s < 8; ++s) {
            float ov = __shfl_xor(bestv[s], off);
            int   oi = __shfl_xor(besti[s], off);
            float os = __shfl_xor(secv[s], off);
            bool owin = (ov < bestv[s]) || (ov == bestv[s] && oi < besti[s]);
            if (owin) { secv[s] = fminf(os, bestv[s]); bestv[s] = ov; besti[s] = oi; }
            else      { secv[s] = fminf(secv[s], ov); }
        }
    }

    if (n == 0) {
        #pragma unroll
        for (int s = 0; s < 8; ++s) {
            int rl = w * 32 + (s >> 2) * 16 + quad * 4 + (s & 3);
            bidx[rl] = besti[s];
            if (secv[s] - bestv[s] <= EPS_MARGIN) {   // fp64 argmin not provable -> flag
                int pos = atomicAdd(counter, 1);
                if (pos < FB_CAP) list[pos] = make_int2(row0 + rl, besti[s]);
            }
        }
    }
    __syncthreads();

    // gather + straight-through output + loss partial (exact-fp32 path)
    double ls = 0.0;
    const int d = t;
    #pragma unroll 4
    for (int r = 0; r < 128; ++r) {
        int code = bidx[r];
        float q  = E[(size_t)d * K_CODES + code];
        float x  = X[(size_t)(row0 + r) * D_DIM + d];
        float dq = q - x;
        out[(size_t)(row0 + r) * D_DIM + d] = x + dq;
        ls += (double)dq * (double)dq;
    }
    #pragma unroll
    for (int off = 32; off > 0; off >>= 1)
        ls += __shfl_down(ls, off);
    if ((t & 63) == 0) atomicAdd(loss_sum, ls);
}

// -------- fp64 exact re-argmin for flagged rows; patch out + loss --------
__global__ void refine_kernel(const float* __restrict__ X, const float* __restrict__ E,
                              float* __restrict__ out, double* __restrict__ loss_sum,
                              const int* __restrict__ counter, const int2* __restrict__ list) {
    __shared__ float xt[D_DIM][FB_RPB];
    __shared__ int rows_sh[FB_RPB], old_sh[FB_RPB], act_sh[FB_RPB], win_sh[FB_RPB];
    __shared__ double wbv[4][FB_RPB];
    __shared__ int    wbi[4][FB_RPB];

    int nf = *counter; if (nf > FB_CAP) nf = FB_CAP;
    const int e0 = blockIdx.x * FB_RPB;
    if (e0 >= nf) return;
    const int t = threadIdx.x;

    if (t < FB_RPB) {
        int e = e0 + t;
        int a = (e < nf) ? 1 : 0;
        int2 ent = list[a ? e : e0];
        rows_sh[t] = ent.x; old_sh[t] = ent.y; act_sh[t] = a;
    }
    __syncthreads();
    #pragma unroll
    for (int j = 0; j < FB_RPB; ++j)
        xt[t][j] = X[(size_t)rows_sh[j] * D_DIM + t];
    __syncthreads();

    double bv[FB_RPB]; int bi[FB_RPB];
    #pragma unroll
    for (int j = 0; j < FB_RPB; ++j) { bv[j] = 1e300; bi[j] = 0; }

    for (int kt = 0; kt < 16; ++kt) {
        const int k0 = kt * 512 + t * 2;
        double s0[FB_RPB], s1[FB_RPB], q0 = 0.0, q1 = 0.0;
        #pragma unroll
        for (int j = 0; j < FB_RPB; ++j) { s0[j] = 0.0; s1[j] = 0.0; }

        for (int d = 0; d < D_DIM; ++d) {
            f2 ev = *(const f2*)(E + (size_t)d * K_CODES + k0);
            double e0d = (double)ev[0], e1d = (double)ev[1];
            const f4* xp = (const f4*)(&xt[d][0]);
            f4 xa = xp[0], xb = xp[1];
            double xd[FB_RPB] = { (double)xa[0], (double)xa[1], (double)xa[2], (double)xa[3],
                                  (double)xb[0], (double)xb[1], (double)xb[2], (double)xb[3] };
            q0 += e0d * e0d; q1 += e1d * e1d;
            #pragma unroll
            for (int j = 0; j < FB_RPB; ++j) {
                s0[j] += xd[j] * e0d;
                s1[j] += xd[j] * e1d;
            }
        }
        #pragma unroll
        for (int j = 0; j < FB_RPB; ++j) {
            double k0v = q0 - 2.0 * s0[j];
            double k1v = q1 - 2.0 * s1[j];
            if (k0v < bv[j]) { bv[j] = k0v; bi[j] = k0; }
            if (k1v < bv[j]) { bv[j] = k1v; bi[j] = k0 + 1; }
        }
    }

    #pragma unroll
    for (int off = 1; off < 64; off <<= 1) {
        #pragma unroll
        for (int j = 0; j < FB_RPB; ++j) {
            double ov = __shfl_xor(bv[j], off);
            int    oi = __shfl_xor(bi[j], off);
            if (ov < bv[j] || (ov == bv[j] && oi < bi[j])) { bv[j] = ov; bi[j] = oi; }
        }
    }
    const int wave = t >> 6;
    if ((t & 63) == 0) {
        #pragma unroll
        for (int j = 0; j < FB_RPB; ++j) { wbv[wave][j] = bv[j]; wbi[wave][j] = bi[j]; }
    }
    __syncthreads();
    if (t < FB_RPB) {
        double b = wbv[0][t]; int i_ = wbi[0][t];
        #pragma unroll
        for (int wv = 1; wv < 4; ++wv) {
            double ov = wbv[wv][t]; int oi = wbi[wv][t];
            if (ov < b || (ov == b && oi < i_)) { b = ov; i_ = oi; }
        }
        win_sh[t] = i_;
    }
    __syncthreads();

    double dl = 0.0;
    #pragma unroll
    for (int j = 0; j < FB_RPB; ++j) {
        if (!act_sh[j]) continue;
        int nc = win_sh[j], oc = old_sh[j];
        if (nc == oc) continue;
        int row = rows_sh[j];
        float x  = xt[t][j];
        float qn = E[(size_t)t * K_CODES + nc];
        float qo = E[(size_t)t * K_CODES + oc];
        float dqn = qn - x, dqo = qo - x;
        out[(size_t)row * D_DIM + t] = x + dqn;
        dl += (double)dqn * dqn - (double)dqo * dqo;
    }
    #pragma unroll
    for (int off = 32; off > 0; off >>= 1)
        dl += __shfl_down(dl, off);
    if ((t & 63) == 0 && dl != 0.0) atomicAdd(loss_sum, dl);
}

// -------- finalize loss = 0.25*m + m --------
__global__ void fin_kernel(const double* __restrict__ loss_sum, float* __restrict__ out) {
    double m = loss_sum[0] / (double)NUM_ELEM;
    out[NUM_ELEM] = (float)(0.25 * m + m);
}

extern "C" void kernel_launch(void* const* d_in, const int* in_sizes, int n_in,
                              void* d_out, int out_size, void* d_ws, size_t ws_size,
                              hipStream_t stream) {
    const float* X = (const float*)d_in[0];   // [32,1024,256] fp32
    const float* E = (const float*)d_in[1];   // [256,8192] fp32
    float* out = (float*)d_out;

    // ws layout: [0,8) loss fp64 | [8,12) counter | ee @1024 (32KB) |
    //            list @36864 (64KB) | Eth @131072 (4MB) | Etl @4325376 (4MB)
    double* loss_sum = (double*)d_ws;
    int*    counter  = (int*)((char*)d_ws + 8);
    float*  ee       = (float*)((char*)d_ws + 1024);
    int2*   list     = (int2*)((char*)d_ws + 36864);
    short*  Eth      = (short*)((char*)d_ws + 131072);
    short*  Etl      = (short*)((char*)d_ws + 131072 + 4194304);

    hipMemsetAsync(d_ws, 0, 1024, stream);
    trans_kernel<<<dim3(128, 4), 256, 0, stream>>>(E, Eth, Etl);
    ee_kernel<<<K_CODES / 256, 256, 0, stream>>>(E, ee);
    mfma_vq_kernel<<<N_ROWS / 128, 256, 0, stream>>>(X, E, Eth, Etl, ee, out,
                                                     loss_sum, counter, list);
    refine_kernel<<<FB_CAP / FB_RPB, 256, 0, stream>>>(X, E, out, loss_sum, counter, list);
    fin_kernel<<<1, 1, 0, stream>>>(loss_sum, out);
}

// Round 4
// 849.689 us; speedup vs baseline: 3.9525x; 2.6392x over previous
//
#include <hip/hip_runtime.h>

typedef float f4   __attribute__((ext_vector_type(4)));
typedef float f2   __attribute__((ext_vector_type(2)));
typedef short bf16x8 __attribute__((ext_vector_type(8)));
typedef float f32x4  __attribute__((ext_vector_type(4)));

#define N_ROWS  32768
#define D_DIM   256
#define K_CODES 8192
#define NUM_ELEM (N_ROWS * D_DIM)
#define EPS_MARGIN 1e-3f     // proven in R2/R3 (bound ~3.7e-4)
#define FB_CAP  8192
#define FB_RPB  8
#define RF_SLICES 16         // 512 codes per refine slice
#define N_PANELS 256         // 32 codes per panel

__device__ __forceinline__ short f2bf(float f) {   // RNE float->bf16 bits
    union { float f; unsigned u; } v; v.f = f;
    unsigned r = v.u + 0x7FFFu + ((v.u >> 16) & 1u);
    return (short)(r >> 16);
}
__device__ __forceinline__ float bf2f(short h) {
    union { unsigned u; float f; } v; v.u = ((unsigned)(unsigned short)h) << 16;
    return v.f;
}
__device__ __forceinline__ void gl2lds16(const void* g, void* l) {
    // async global->LDS, 16B/lane; LDS dest = wave-uniform base + lane*16
    __builtin_amdgcn_global_load_lds(
        (const __attribute__((address_space(1))) unsigned int*)g,
        (__attribute__((address_space(3))) unsigned int*)l, 16, 0, 0);
}

// -------- ee[k] = sum_d E[d][k]^2 (fp64 accumulate, round once) --------
__global__ void ee_kernel(const float* __restrict__ E, float* __restrict__ ee) {
    const int k = blockIdx.x * blockDim.x + threadIdx.x;
    double s = 0.0;
    for (int d = 0; d < D_DIM; ++d) {
        float v = E[(size_t)d * K_CODES + k];
        s += (double)v * (double)v;
    }
    ee[k] = (float)s;
}

// -------- Ep: panel-major bf16 h/l split; panel = 32 codes, LDS-image layout --------
// panel p shorts [p*16384, +16384): h granule (g,c) at (g*32+c)*8, l at +8192
__global__ void prep_kernel(const float* __restrict__ E, short* __restrict__ Ep) {
    const int p  = blockIdx.x;
    const int t  = threadIdx.x;
    const int c  = t & 31;
    const int gq = t >> 5;             // 0..7, 4 granules each
    const int cp = p * 32;
    short* ph = Ep + (size_t)p * 16384;
    short* pl = ph + 8192;
    #pragma unroll
    for (int gi = 0; gi < 4; ++gi) {
        int g = gq * 4 + gi;
        bf16x8 h, l;
        #pragma unroll
        for (int j = 0; j < 8; ++j) {
            float v = E[(size_t)(g * 8 + j) * K_CODES + cp + c];
            short hh = f2bf(v);
            h[j] = hh;
            l[j] = f2bf(v - bf2f(hh));
        }
        *(bf16x8*)(ph + (g * 32 + c) * 8) = h;
        *(bf16x8*)(pl + (g * 32 + c) * 8) = l;
    }
}

// -------- Et32[k][d] = E[d][k] (exact fp32 transpose, for coalesced gathers) --------
__global__ void trans32_kernel(const float* __restrict__ E, float* __restrict__ Et32) {
    __shared__ float tile[64][65];
    const int t  = threadIdx.x;
    const int k0 = blockIdx.x * 64, d0 = blockIdx.y * 64;
    #pragma unroll
    for (int i = 0; i < 16; ++i) {
        int dd = i * 4 + (t >> 6), kk = t & 63;
        tile[dd][kk] = E[(size_t)(d0 + dd) * K_CODES + k0 + kk];
    }
    __syncthreads();
    #pragma unroll
    for (int i = 0; i < 16; ++i) {
        int kk = i * 4 + (t >> 6), dd = t & 63;
        Et32[(size_t)(k0 + kk) * D_DIM + d0 + dd] = tile[dd][kk];
    }
}

// -------- MFMA sieve: async-staged bf16-split GEMM + top-2 argmin + out/loss --------
__launch_bounds__(256, 1)
__global__ void mfma_vq_kernel(const float* __restrict__ X,
                               const short* __restrict__ Ep,
                               const float* __restrict__ Et32,
                               const float* __restrict__ ee, float* __restrict__ out,
                               double* __restrict__ loss_sum, int* __restrict__ counter,
                               int2* __restrict__ list) {
    __shared__ __align__(16) short Bbuf[2][16384];   // 2 x 32 KB panels (h | l)
    const int t    = threadIdx.x;
    const int w    = t >> 6;
    const int lane = t & 63;
    const int n    = lane & 15;
    const int quad = lane >> 4;
    const int row0 = blockIdx.x * 128;
    const int rw   = row0 + w * 32;

    // ---- A fragments (32 rows x 256 d, h+l) -> registers (same as R3) ----
    bf16x8 Ah[2][8], Al[2][8];
    #pragma unroll
    for (int rt = 0; rt < 2; ++rt) {
        const float* xp = X + (size_t)(rw + rt * 16 + n) * D_DIM;
        #pragma unroll
        for (int ks = 0; ks < 8; ++ks) {
            int d = ks * 32 + quad * 8;
            f4 a = *(const f4*)(xp + d);
            f4 b = *(const f4*)(xp + d + 4);
            bf16x8 h, l;
            #pragma unroll
            for (int j = 0; j < 8; ++j) {
                float x = (j < 4) ? a[j] : b[j - 4];
                short hh = f2bf(x);
                h[j] = hh;
                l[j] = f2bf(x - bf2f(hh));
            }
            Ah[rt][ks] = h; Al[rt][ks] = l;
        }
    }

    float bestv[8], secv[8]; int besti[8];
    #pragma unroll
    for (int s = 0; s < 8; ++s) { bestv[s] = 1e30f; secv[s] = 1e30f; besti[s] = 0; }

    // ---- prime: panel 0 -> buf 0 (8 x 1KB segments per wave) ----
    {
        const char* gp = (const char*)Ep;
        char* lp = (char*)&Bbuf[0][0];
        #pragma unroll
        for (int i = 0; i < 8; ++i)
            gl2lds16(gp + (w * 8 + i) * 1024 + lane * 16, lp + (w * 8 + i) * 1024);
    }
    __syncthreads();   // barrier drains vmcnt -> panel 0 resident

    for (int p = 0; p < N_PANELS; ++p) {
        const int buf = p & 1;
        if (p + 1 < N_PANELS) {        // prefetch next panel; overlaps MFMA below
            const char* gp = (const char*)Ep + (size_t)(p + 1) * 32768;
            char* lp = (char*)&Bbuf[buf ^ 1][0];
            #pragma unroll
            for (int i = 0; i < 8; ++i)
                gl2lds16(gp + (w * 8 + i) * 1024 + lane * 16, lp + (w * 8 + i) * 1024);
        }

        const short* Bh = &Bbuf[buf][0];
        const short* Bl = &Bbuf[buf][8192];

        f32x4 acc[2][2];
        #pragma unroll
        for (int ct = 0; ct < 2; ++ct)
            #pragma unroll
            for (int rt = 0; rt < 2; ++rt)
                acc[ct][rt] = (f32x4)(0.0f);

        #pragma unroll
        for (int ks = 0; ks < 8; ++ks) {
            const int g = ks * 4 + quad;
            bf16x8 bh[2], bl[2];
            #pragma unroll
            for (int ct = 0; ct < 2; ++ct) {
                int c = ct * 16 + n;
                bh[ct] = *(const bf16x8*)(Bh + (g * 32 + c) * 8);
                bl[ct] = *(const bf16x8*)(Bl + (g * 32 + c) * 8);
            }
            #pragma unroll
            for (int ct = 0; ct < 2; ++ct)
                #pragma unroll
                for (int rt = 0; rt < 2; ++rt) {
                    acc[ct][rt] = __builtin_amdgcn_mfma_f32_16x16x32_bf16(Ah[rt][ks], bh[ct], acc[ct][rt], 0, 0, 0);
                    acc[ct][rt] = __builtin_amdgcn_mfma_f32_16x16x32_bf16(Al[rt][ks], bh[ct], acc[ct][rt], 0, 0, 0);
                    acc[ct][rt] = __builtin_amdgcn_mfma_f32_16x16x32_bf16(Ah[rt][ks], bl[ct], acc[ct][rt], 0, 0, 0);
                }
        }

        const int cb = p * 32;
        #pragma unroll
        for (int ct = 0; ct < 2; ++ct) {
            int code = cb + ct * 16 + n;
            float eev = ee[code];
            #pragma unroll
            for (int rt = 0; rt < 2; ++rt)
                #pragma unroll
                for (int r = 0; r < 4; ++r) {
                    float key = fmaf(-2.0f, acc[ct][rt][r], eev);
                    int s = rt * 4 + r;
                    if (key < bestv[s]) { secv[s] = bestv[s]; bestv[s] = key; besti[s] = code; }
                    else if (key < secv[s]) { secv[s] = key; }
                }
        }
        __syncthreads();   // reads of buf done; prefetch into buf^1 drained
    }

    // ---- top-2 merge across the 16 'n' lanes ----
    #pragma unroll
    for (int off = 1; off < 16; off <<= 1) {
        #pragma unroll
        for (int s = 0; s < 8; ++s) {
            float ov = __shfl_xor(bestv[s], off);
            int   oi = __shfl_xor(besti[s], off);
            float os = __shfl_xor(secv[s], off);
            bool owin = (ov < bestv[s]) || (ov == bestv[s] && oi < besti[s]);
            if (owin) { secv[s] = fminf(os, bestv[s]); bestv[s] = ov; besti[s] = oi; }
            else      { secv[s] = fminf(secv[s], ov); }
        }
    }

    int* bidx = (int*)&Bbuf[0][0];     // LDS reuse (K loop complete)
    if (n == 0) {
        #pragma unroll
        for (int s = 0; s < 8; ++s) {
            int rl = w * 32 + (s >> 2) * 16 + quad * 4 + (s & 3);
            bidx[rl] = besti[s];
            if (secv[s] - bestv[s] <= EPS_MARGIN) {
                int pos = atomicAdd(counter, 1);
                if (pos < FB_CAP) list[pos] = make_int2(row0 + rl, besti[s]);
            }
        }
    }
    __syncthreads();

    // ---- gather (coalesced via Et32) + straight-through output + loss ----
    double ls = 0.0;
    const int d = t;
    #pragma unroll 4
    for (int r = 0; r < 128; ++r) {
        int code = bidx[r];
        float q  = Et32[(size_t)code * D_DIM + d];
        float x  = X[(size_t)(row0 + r) * D_DIM + d];
        float dq = q - x;
        out[(size_t)(row0 + r) * D_DIM + d] = x + dq;
        ls += (double)dq * (double)dq;
    }
    #pragma unroll
    for (int off = 32; off > 0; off >>= 1)
        ls += __shfl_down(ls, off);
    if ((t & 63) == 0) atomicAdd(loss_sum, ls);
}

// -------- refine phase 1: fp64 keys, items = (row-chunk x 16 slices) --------
__global__ void refine1_kernel(const float* __restrict__ X, const float* __restrict__ E,
                               const int* __restrict__ counter, const int2* __restrict__ list,
                               double* __restrict__ res_v, int* __restrict__ res_i) {
    __shared__ float xt[D_DIM][FB_RPB];
    __shared__ int rows_sh[FB_RPB];
    __shared__ double wbv[4][FB_RPB];
    __shared__ int    wbi[4][FB_RPB];

    int nf = *counter; if (nf > FB_CAP) nf = FB_CAP;
    const int nchunks = (nf + FB_RPB - 1) / FB_RPB;
    const int nitems  = nchunks * RF_SLICES;
    const int t = threadIdx.x;

    for (int item = blockIdx.x; item < nitems; item += gridDim.x) {
        const int rc = item / RF_SLICES;
        const int sl = item % RF_SLICES;
        __syncthreads();                      // guard xt/wbv reuse across items
        if (t < FB_RPB) {
            int e = rc * FB_RPB + t;
            int2 ent = list[(e < nf) ? e : 0];
            rows_sh[t] = ent.x;
        }
        __syncthreads();
        #pragma unroll
        for (int j = 0; j < FB_RPB; ++j)
            xt[t][j] = X[(size_t)rows_sh[j] * D_DIM + t];
        __syncthreads();

        // identical fp64 op-order to the R2/R3-passing refine: d ascending, q - 2.0*s
        const int k0 = sl * 512 + t * 2;
        double s0[FB_RPB], s1[FB_RPB], q0 = 0.0, q1 = 0.0;
        #pragma unroll
        for (int j = 0; j < FB_RPB; ++j) { s0[j] = 0.0; s1[j] = 0.0; }
        for (int d = 0; d < D_DIM; ++d) {
            f2 ev = *(const f2*)(E + (size_t)d * K_CODES + k0);
            double e0d = (double)ev[0], e1d = (double)ev[1];
            const f4* xp = (const f4*)(&xt[d][0]);
            f4 xa = xp[0], xb = xp[1];
            double xd[FB_RPB] = { (double)xa[0], (double)xa[1], (double)xa[2], (double)xa[3],
                                  (double)xb[0], (double)xb[1], (double)xb[2], (double)xb[3] };
            q0 += e0d * e0d; q1 += e1d * e1d;
            #pragma unroll
            for (int j = 0; j < FB_RPB; ++j) {
                s0[j] += xd[j] * e0d;
                s1[j] += xd[j] * e1d;
            }
        }
        double bv[FB_RPB]; int bi[FB_RPB];
        #pragma unroll
        for (int j = 0; j < FB_RPB; ++j) {
            double k0v = q0 - 2.0 * s0[j];
            double k1v = q1 - 2.0 * s1[j];
            bv[j] = k0v; bi[j] = k0;
            if (k1v < bv[j]) { bv[j] = k1v; bi[j] = k0 + 1; }
        }
        #pragma unroll
        for (int off = 1; off < 64; off <<= 1) {
            #pragma unroll
            for (int j = 0; j < FB_RPB; ++j) {
                double ov = __shfl_xor(bv[j], off);
                int    oi = __shfl_xor(bi[j], off);
                if (ov < bv[j] || (ov == bv[j] && oi < bi[j])) { bv[j] = ov; bi[j] = oi; }
            }
        }
        const int wave = t >> 6;
        if ((t & 63) == 0) {
            #pragma unroll
            for (int j = 0; j < FB_RPB; ++j) { wbv[wave][j] = bv[j]; wbi[wave][j] = bi[j]; }
        }
        __syncthreads();
        if (t < FB_RPB) {
            double b = wbv[0][t]; int i_ = wbi[0][t];
            #pragma unroll
            for (int wv = 1; wv < 4; ++wv) {
                double ov = wbv[wv][t]; int oi = wbi[wv][t];
                if (ov < b || (ov == b && oi < i_)) { b = ov; i_ = oi; }
            }
            int e = rc * FB_RPB + t;              // < nchunks*8 <= FB_CAP
            res_v[(size_t)e * RF_SLICES + sl] = b;
            res_i[(size_t)e * RF_SLICES + sl] = i_;
        }
    }
}

// -------- refine phase 2: pick fp64 winner, patch row + loss --------
__global__ void patch_kernel(const float* __restrict__ X, const float* __restrict__ Et32,
                             float* __restrict__ out, double* __restrict__ loss_sum,
                             const int* __restrict__ counter, const int2* __restrict__ list,
                             const double* __restrict__ res_v, const int* __restrict__ res_i) {
    int nf = *counter; if (nf > FB_CAP) nf = FB_CAP;
    const int b = blockIdx.x;
    if (b >= nf) return;
    __shared__ int nc_sh;
    const int t = threadIdx.x;
    if (t == 0) {
        double bv = res_v[(size_t)b * RF_SLICES]; int bi = res_i[(size_t)b * RF_SLICES];
        for (int s = 1; s < RF_SLICES; ++s) {     // ascending slices: lowest-index ties
            double v = res_v[(size_t)b * RF_SLICES + s];
            int    i = res_i[(size_t)b * RF_SLICES + s];
            if (v < bv || (v == bv && i < bi)) { bv = v; bi = i; }
        }
        nc_sh = bi;
    }
    __syncthreads();
    int2 ent = list[b];
    const int oc = ent.y, row = ent.x, nc = nc_sh;
    if (nc == oc) return;
    float x  = X[(size_t)row * D_DIM + t];
    float qn = Et32[(size_t)nc * D_DIM + t];
    float qo = Et32[(size_t)oc * D_DIM + t];
    float dqn = qn - x, dqo = qo - x;
    out[(size_t)row * D_DIM + t] = x + dqn;
    double dl = (double)dqn * dqn - (double)dqo * dqo;
    #pragma unroll
    for (int off = 32; off > 0; off >>= 1)
        dl += __shfl_down(dl, off);
    if ((t & 63) == 0) atomicAdd(loss_sum, dl);
}

// -------- finalize loss = 0.25*m + m --------
__global__ void fin_kernel(const double* __restrict__ loss_sum, float* __restrict__ out) {
    double m = loss_sum[0] / (double)NUM_ELEM;
    out[NUM_ELEM] = (float)(0.25 * m + m);
}

extern "C" void kernel_launch(void* const* d_in, const int* in_sizes, int n_in,
                              void* d_out, int out_size, void* d_ws, size_t ws_size,
                              hipStream_t stream) {
    const float* X = (const float*)d_in[0];   // [32,1024,256] fp32
    const float* E = (const float*)d_in[1];   // [256,8192] fp32
    float* out = (float*)d_out;

    // ws: loss@0 | counter@8 | ee@1024 (32K) | list@36864 (64K) |
    //     res_v@131072 (1M) | res_i@1179648 (512K) | Et32@1703936 (8M) | Ep@10092544 (8M)
    double* loss_sum = (double*)d_ws;
    int*    counter  = (int*)((char*)d_ws + 8);
    float*  ee       = (float*)((char*)d_ws + 1024);
    int2*   list     = (int2*)((char*)d_ws + 36864);
    double* res_v    = (double*)((char*)d_ws + 131072);
    int*    res_i    = (int*)((char*)d_ws + 1179648);
    float*  Et32     = (float*)((char*)d_ws + 1703936);
    short*  Ep       = (short*)((char*)d_ws + 10092544);

    hipMemsetAsync(d_ws, 0, 1024, stream);
    prep_kernel<<<N_PANELS, 256, 0, stream>>>(E, Ep);
    trans32_kernel<<<dim3(128, 4), 256, 0, stream>>>(E, Et32);
    ee_kernel<<<K_CODES / 256, 256, 0, stream>>>(E, ee);
    mfma_vq_kernel<<<N_ROWS / 128, 256, 0, stream>>>(X, Ep, Et32, ee, out,
                                                     loss_sum, counter, list);
    refine1_kernel<<<2048, 256, 0, stream>>>(X, E, counter, list, res_v, res_i);
    patch_kernel<<<FB_CAP, 256, 0, stream>>>(X, Et32, out, loss_sum, counter, list,
                                             res_v, res_i);
    fin_kernel<<<1, 1, 0, stream>>>(loss_sum, out);
}

// Round 5
// 517.287 us; speedup vs baseline: 6.4923x; 1.6426x over previous
//
#include <hip/hip_runtime.h>

typedef float f4   __attribute__((ext_vector_type(4)));
typedef float f2   __attribute__((ext_vector_type(2)));
typedef short bf16x8 __attribute__((ext_vector_type(8)));
typedef float f32x4  __attribute__((ext_vector_type(4)));

#define N_ROWS  32768
#define D_DIM   256
#define K_CODES 8192
#define NUM_ELEM (N_ROWS * D_DIM)
#define EPS_MARGIN 1e-3f     // proven in R2-R4
#define FB_CAP  8192
#define FB_RPB  8
#define RF_SLICES 16
#define N_PANELS 256         // 32 codes per panel
#define HALF_PANELS 128      // panels per code-half

__device__ __forceinline__ short f2bf(float f) {
    union { float f; unsigned u; } v; v.f = f;
    unsigned r = v.u + 0x7FFFu + ((v.u >> 16) & 1u);
    return (short)(r >> 16);
}
__device__ __forceinline__ float bf2f(short h) {
    union { unsigned u; float f; } v; v.u = ((unsigned)(unsigned short)h) << 16;
    return v.f;
}
__device__ __forceinline__ void gl2lds16(const void* g, void* l) {
    __builtin_amdgcn_global_load_lds(
        (const __attribute__((address_space(1))) unsigned int*)g,
        (__attribute__((address_space(3))) unsigned int*)l, 16, 0, 0);
}

// -------- ee[k] = sum_d E[d][k]^2 --------
__global__ void ee_kernel(const float* __restrict__ E, float* __restrict__ ee) {
    const int k = blockIdx.x * blockDim.x + threadIdx.x;
    double s = 0.0;
    for (int d = 0; d < D_DIM; ++d) {
        float v = E[(size_t)d * K_CODES + k];
        s += (double)v * (double)v;
    }
    ee[k] = (float)s;
}

// -------- Ep: panel-major bf16 h/l split (LDS-image layout) --------
__global__ void prep_kernel(const float* __restrict__ E, short* __restrict__ Ep) {
    const int p  = blockIdx.x;
    const int t  = threadIdx.x;
    const int c  = t & 31;
    const int gq = t >> 5;
    const int cp = p * 32;
    short* ph = Ep + (size_t)p * 16384;
    short* pl = ph + 8192;
    #pragma unroll
    for (int gi = 0; gi < 4; ++gi) {
        int g = gq * 4 + gi;
        bf16x8 h, l;
        #pragma unroll
        for (int j = 0; j < 8; ++j) {
            float v = E[(size_t)(g * 8 + j) * K_CODES + cp + c];
            short hh = f2bf(v);
            h[j] = hh;
            l[j] = f2bf(v - bf2f(hh));
        }
        *(bf16x8*)(ph + (g * 32 + c) * 8) = h;
        *(bf16x8*)(pl + (g * 32 + c) * 8) = l;
    }
}

// -------- Et32[k][d] = E[d][k] --------
__global__ void trans32_kernel(const float* __restrict__ E, float* __restrict__ Et32) {
    __shared__ float tile[64][65];
    const int t  = threadIdx.x;
    const int k0 = blockIdx.x * 64, d0 = blockIdx.y * 64;
    #pragma unroll
    for (int i = 0; i < 16; ++i) {
        int dd = i * 4 + (t >> 6), kk = t & 63;
        tile[dd][kk] = E[(size_t)(d0 + dd) * K_CODES + k0 + kk];
    }
    __syncthreads();
    #pragma unroll
    for (int i = 0; i < 16; ++i) {
        int kk = i * 4 + (t >> 6), dd = t & 63;
        Et32[(size_t)(k0 + kk) * D_DIM + d0 + dd] = tile[dd][kk];
    }
}

// -------- MFMA sieve: grid 512 = (row-tile 256) x (code-half 2) --------
__launch_bounds__(256, 2)
__global__ void mfma_sieve_kernel(const float* __restrict__ X,
                                  const short* __restrict__ Ep,
                                  const float* __restrict__ ee,
                                  f2* __restrict__ res_bs,     // [row*2+half] = (best, sec)
                                  int* __restrict__ res_idx) { // [row*2+half]
    __shared__ __align__(16) short Bbuf[2][16384];   // 2 x 32 KB
    const int t    = threadIdx.x;
    const int w    = t >> 6;
    const int lane = t & 63;
    const int n    = lane & 15;
    const int quad = lane >> 4;
    const int half = blockIdx.x & 1;
    const int row0 = (blockIdx.x >> 1) * 128;
    const int rw   = row0 + w * 32;
    const int p0   = half * HALF_PANELS;

    // ---- A fragments (32 rows x 256 d, h+l) -> registers (identical to R3/R4) ----
    bf16x8 Ah[2][8], Al[2][8];
    #pragma unroll
    for (int rt = 0; rt < 2; ++rt) {
        const float* xp = X + (size_t)(rw + rt * 16 + n) * D_DIM;
        #pragma unroll
        for (int ks = 0; ks < 8; ++ks) {
            int d = ks * 32 + quad * 8;
            f4 a = *(const f4*)(xp + d);
            f4 b = *(const f4*)(xp + d + 4);
            bf16x8 h, l;
            #pragma unroll
            for (int j = 0; j < 8; ++j) {
                float x = (j < 4) ? a[j] : b[j - 4];
                short hh = f2bf(x);
                h[j] = hh;
                l[j] = f2bf(x - bf2f(hh));
            }
            Ah[rt][ks] = h; Al[rt][ks] = l;
        }
    }

    float bestv[8], secv[8]; int besti[8];
    #pragma unroll
    for (int s = 0; s < 8; ++s) { bestv[s] = 1e30f; secv[s] = 1e30f; besti[s] = 0; }

    {   // prime panel p0 -> buf 0
        const char* gp = (const char*)Ep + (size_t)p0 * 32768;
        char* lp = (char*)&Bbuf[0][0];
        #pragma unroll
        for (int i = 0; i < 8; ++i)
            gl2lds16(gp + (w * 8 + i) * 1024 + lane * 16, lp + (w * 8 + i) * 1024);
    }
    __syncthreads();

    for (int i = 0; i < HALF_PANELS; ++i) {
        const int p   = p0 + i;
        const int buf = i & 1;
        if (i + 1 < HALF_PANELS) {
            const char* gp = (const char*)Ep + (size_t)(p + 1) * 32768;
            char* lp = (char*)&Bbuf[buf ^ 1][0];
            #pragma unroll
            for (int k = 0; k < 8; ++k)
                gl2lds16(gp + (w * 8 + k) * 1024 + lane * 16, lp + (w * 8 + k) * 1024);
        }

        const short* Bh = &Bbuf[buf][0];
        const short* Bl = &Bbuf[buf][8192];

        f32x4 acc[2][2];
        #pragma unroll
        for (int ct = 0; ct < 2; ++ct)
            #pragma unroll
            for (int rt = 0; rt < 2; ++rt)
                acc[ct][rt] = (f32x4)(0.0f);

        #pragma unroll
        for (int ks = 0; ks < 8; ++ks) {
            const int g = ks * 4 + quad;
            bf16x8 bh[2], bl[2];
            #pragma unroll
            for (int ct = 0; ct < 2; ++ct) {
                int c = ct * 16 + n;
                bh[ct] = *(const bf16x8*)(Bh + (g * 32 + c) * 8);
                bl[ct] = *(const bf16x8*)(Bl + (g * 32 + c) * 8);
            }
            #pragma unroll
            for (int ct = 0; ct < 2; ++ct)
                #pragma unroll
                for (int rt = 0; rt < 2; ++rt) {
                    acc[ct][rt] = __builtin_amdgcn_mfma_f32_16x16x32_bf16(Ah[rt][ks], bh[ct], acc[ct][rt], 0, 0, 0);
                    acc[ct][rt] = __builtin_amdgcn_mfma_f32_16x16x32_bf16(Al[rt][ks], bh[ct], acc[ct][rt], 0, 0, 0);
                    acc[ct][rt] = __builtin_amdgcn_mfma_f32_16x16x32_bf16(Ah[rt][ks], bl[ct], acc[ct][rt], 0, 0, 0);
                }
        }

        const int cb = p * 32;
        #pragma unroll
        for (int ct = 0; ct < 2; ++ct) {
            int code = cb + ct * 16 + n;
            float eev = ee[code];
            #pragma unroll
            for (int rt = 0; rt < 2; ++rt)
                #pragma unroll
                for (int r = 0; r < 4; ++r) {
                    float key = fmaf(-2.0f, acc[ct][rt][r], eev);
                    int s = rt * 4 + r;
                    // min/max form; strict-< index semantics preserved
                    float nb = fminf(key, bestv[s]);
                    secv[s]  = fminf(secv[s], fmaxf(key, bestv[s]));
                    besti[s] = (key < bestv[s]) ? code : besti[s];
                    bestv[s] = nb;
                }
        }
        __syncthreads();
    }

    // top-2 merge across the 16 'n' lanes
    #pragma unroll
    for (int off = 1; off < 16; off <<= 1) {
        #pragma unroll
        for (int s = 0; s < 8; ++s) {
            float ov = __shfl_xor(bestv[s], off);
            int   oi = __shfl_xor(besti[s], off);
            float os = __shfl_xor(secv[s], off);
            bool owin = (ov < bestv[s]) || (ov == bestv[s] && oi < besti[s]);
            if (owin) { secv[s] = fminf(os, bestv[s]); bestv[s] = ov; besti[s] = oi; }
            else      { secv[s] = fminf(secv[s], ov); }
        }
    }

    if (n == 0) {
        #pragma unroll
        for (int s = 0; s < 8; ++s) {
            int rl  = w * 32 + (s >> 2) * 16 + quad * 4 + (s & 3);
            int row = row0 + rl;
            f2 bs; bs[0] = bestv[s]; bs[1] = secv[s];
            res_bs[(size_t)row * 2 + half]  = bs;
            res_idx[(size_t)row * 2 + half] = besti[s];
        }
    }
}

// -------- merge halves: final bidx + EPS flagging --------
__global__ void merge_kernel(const f2* __restrict__ res_bs, const int* __restrict__ res_idx,
                             int* __restrict__ bidx, int* __restrict__ counter,
                             int2* __restrict__ list) {
    const int row = blockIdx.x * blockDim.x + threadIdx.x;
    if (row >= N_ROWS) return;
    f2 a = res_bs[(size_t)row * 2];      // half 0 (indices < half 1's)
    f2 b = res_bs[(size_t)row * 2 + 1];
    int ia = res_idx[(size_t)row * 2];
    int ib = res_idx[(size_t)row * 2 + 1];
    float gb; int gi; float gs;
    if (b[0] < a[0]) { gb = b[0]; gi = ib; gs = fminf(b[1], a[0]); }
    else             { gb = a[0]; gi = ia; gs = fminf(a[1], b[0]); }  // tie -> half 0 (lower idx)
    bidx[row] = gi;
    if (gs - gb <= EPS_MARGIN) {
        int pos = atomicAdd(counter, 1);
        if (pos < FB_CAP) list[pos] = make_int2(row, gi);
    }
}

// -------- gather + straight-through output + loss (same op order as R4 tail) --------
__global__ void gather_kernel(const float* __restrict__ X, const float* __restrict__ Et32,
                              const int* __restrict__ bidx, float* __restrict__ out,
                              double* __restrict__ loss_sum) {
    __shared__ int bl_[128];
    const int t    = threadIdx.x;
    const int row0 = blockIdx.x * 128;
    if (t < 128) bl_[t] = bidx[row0 + t];
    __syncthreads();
    double ls = 0.0;
    const int d = t;
    #pragma unroll 4
    for (int r = 0; r < 128; ++r) {
        int code = bl_[r];
        float q  = Et32[(size_t)code * D_DIM + d];
        float x  = X[(size_t)(row0 + r) * D_DIM + d];
        float dq = q - x;
        out[(size_t)(row0 + r) * D_DIM + d] = x + dq;
        ls += (double)dq * (double)dq;
    }
    #pragma unroll
    for (int off = 32; off > 0; off >>= 1)
        ls += __shfl_down(ls, off);
    if ((t & 63) == 0) atomicAdd(loss_sum, ls);
}

// -------- refine phase 1: fp64 keys over (row-chunk x 16 slices) --------
__global__ void refine1_kernel(const float* __restrict__ X, const float* __restrict__ E,
                               const int* __restrict__ counter, const int2* __restrict__ list,
                               double* __restrict__ res_v, int* __restrict__ res_i) {
    __shared__ float xt[D_DIM][FB_RPB];
    __shared__ int rows_sh[FB_RPB];
    __shared__ double wbv[4][FB_RPB];
    __shared__ int    wbi[4][FB_RPB];

    int nf = *counter; if (nf > FB_CAP) nf = FB_CAP;
    const int nchunks = (nf + FB_RPB - 1) / FB_RPB;
    const int nitems  = nchunks * RF_SLICES;
    const int t = threadIdx.x;

    for (int item = blockIdx.x; item < nitems; item += gridDim.x) {
        const int rc = item / RF_SLICES;
        const int sl = item % RF_SLICES;
        __syncthreads();
        if (t < FB_RPB) {
            int e = rc * FB_RPB + t;
            int2 ent = list[(e < nf) ? e : 0];
            rows_sh[t] = ent.x;
        }
        __syncthreads();
        #pragma unroll
        for (int j = 0; j < FB_RPB; ++j)
            xt[t][j] = X[(size_t)rows_sh[j] * D_DIM + t];
        __syncthreads();

        const int k0 = sl * 512 + t * 2;
        double s0[FB_RPB], s1[FB_RPB], q0 = 0.0, q1 = 0.0;
        #pragma unroll
        for (int j = 0; j < FB_RPB; ++j) { s0[j] = 0.0; s1[j] = 0.0; }
        for (int d = 0; d < D_DIM; ++d) {
            f2 ev = *(const f2*)(E + (size_t)d * K_CODES + k0);
            double e0d = (double)ev[0], e1d = (double)ev[1];
            const f4* xp = (const f4*)(&xt[d][0]);
            f4 xa = xp[0], xb = xp[1];
            double xd[FB_RPB] = { (double)xa[0], (double)xa[1], (double)xa[2], (double)xa[3],
                                  (double)xb[0], (double)xb[1], (double)xb[2], (double)xb[3] };
            q0 += e0d * e0d; q1 += e1d * e1d;
            #pragma unroll
            for (int j = 0; j < FB_RPB; ++j) {
                s0[j] += xd[j] * e0d;
                s1[j] += xd[j] * e1d;
            }
        }
        double bv[FB_RPB]; int bi[FB_RPB];
        #pragma unroll
        for (int j = 0; j < FB_RPB; ++j) {
            double k0v = q0 - 2.0 * s0[j];
            double k1v = q1 - 2.0 * s1[j];
            bv[j] = k0v; bi[j] = k0;
            if (k1v < bv[j]) { bv[j] = k1v; bi[j] = k0 + 1; }
        }
        #pragma unroll
        for (int off = 1; off < 64; off <<= 1) {
            #pragma unroll
            for (int j = 0; j < FB_RPB; ++j) {
                double ov = __shfl_xor(bv[j], off);
                int    oi = __shfl_xor(bi[j], off);
                if (ov < bv[j] || (ov == bv[j] && oi < bi[j])) { bv[j] = ov; bi[j] = oi; }
            }
        }
        const int wave = t >> 6;
        if ((t & 63) == 0) {
            #pragma unroll
            for (int j = 0; j < FB_RPB; ++j) { wbv[wave][j] = bv[j]; wbi[wave][j] = bi[j]; }
        }
        __syncthreads();
        if (t < FB_RPB) {
            double b = wbv[0][t]; int i_ = wbi[0][t];
            #pragma unroll
            for (int wv = 1; wv < 4; ++wv) {
                double ov = wbv[wv][t]; int oi = wbi[wv][t];
                if (ov < b || (ov == b && oi < i_)) { b = ov; i_ = oi; }
            }
            int e = rc * FB_RPB + t;
            res_v[(size_t)e * RF_SLICES + sl] = b;
            res_i[(size_t)e * RF_SLICES + sl] = i_;
        }
    }
}

// -------- refine phase 2: pick fp64 winner, patch row + loss --------
__global__ void patch_kernel(const float* __restrict__ X, const float* __restrict__ Et32,
                             float* __restrict__ out, double* __restrict__ loss_sum,
                             const int* __restrict__ counter, const int2* __restrict__ list,
                             const double* __restrict__ res_v, const int* __restrict__ res_i) {
    int nf = *counter; if (nf > FB_CAP) nf = FB_CAP;
    const int b = blockIdx.x;
    if (b >= nf) return;
    __shared__ int nc_sh;
    const int t = threadIdx.x;
    if (t == 0) {
        double bv = res_v[(size_t)b * RF_SLICES]; int bi = res_i[(size_t)b * RF_SLICES];
        for (int s = 1; s < RF_SLICES; ++s) {
            double v = res_v[(size_t)b * RF_SLICES + s];
            int    i = res_i[(size_t)b * RF_SLICES + s];
            if (v < bv || (v == bv && i < bi)) { bv = v; bi = i; }
        }
        nc_sh = bi;
    }
    __syncthreads();
    int2 ent = list[b];
    const int oc = ent.y, row = ent.x, nc = nc_sh;
    if (nc == oc) return;
    float x  = X[(size_t)row * D_DIM + t];
    float qn = Et32[(size_t)nc * D_DIM + t];
    float qo = Et32[(size_t)oc * D_DIM + t];
    float dqn = qn - x, dqo = qo - x;
    out[(size_t)row * D_DIM + t] = x + dqn;
    double dl = (double)dqn * dqn - (double)dqo * dqo;
    #pragma unroll
    for (int off = 32; off > 0; off >>= 1)
        dl += __shfl_down(dl, off);
    if ((t & 63) == 0) atomicAdd(loss_sum, dl);
}

// -------- finalize loss --------
__global__ void fin_kernel(const double* __restrict__ loss_sum, float* __restrict__ out) {
    double m = loss_sum[0] / (double)NUM_ELEM;
    out[NUM_ELEM] = (float)(0.25 * m + m);
}

extern "C" void kernel_launch(void* const* d_in, const int* in_sizes, int n_in,
                              void* d_out, int out_size, void* d_ws, size_t ws_size,
                              hipStream_t stream) {
    const float* X = (const float*)d_in[0];   // [32,1024,256] fp32
    const float* E = (const float*)d_in[1];   // [256,8192] fp32
    float* out = (float*)d_out;

    // ws layout
    double* loss_sum = (double*)d_ws;                          // 8 B
    int*    counter  = (int*)((char*)d_ws + 8);                // 4 B
    float*  ee       = (float*)((char*)d_ws + 1024);           // 32 KB
    int2*   list     = (int2*)((char*)d_ws + 36864);           // 64 KB
    double* res_v    = (double*)((char*)d_ws + 131072);        // 1 MB
    int*    res_i    = (int*)((char*)d_ws + 1179648);          // 512 KB
    float*  Et32     = (float*)((char*)d_ws + 1703936);        // 8 MB
    short*  Ep       = (short*)((char*)d_ws + 10092544);       // 8 MB
    f2*     res_bs   = (f2*)((char*)d_ws + 18481152);          // 512 KB (65536 x f2)
    int*    res_idx  = (int*)((char*)d_ws + 19005440);         // 256 KB
    int*    bidx     = (int*)((char*)d_ws + 19267584);         // 128 KB

    hipMemsetAsync(d_ws, 0, 1024, stream);
    prep_kernel<<<N_PANELS, 256, 0, stream>>>(E, Ep);
    trans32_kernel<<<dim3(128, 4), 256, 0, stream>>>(E, Et32);
    ee_kernel<<<K_CODES / 256, 256, 0, stream>>>(E, ee);
    mfma_sieve_kernel<<<512, 256, 0, stream>>>(X, Ep, ee, res_bs, res_idx);
    merge_kernel<<<N_ROWS / 256, 256, 0, stream>>>(res_bs, res_idx, bidx, counter, list);
    gather_kernel<<<N_ROWS / 128, 256, 0, stream>>>(X, Et32, bidx, out, loss_sum);
    refine1_kernel<<<2048, 256, 0, stream>>>(X, E, counter, list, res_v, res_i);
    patch_kernel<<<FB_CAP, 256, 0, stream>>>(X, Et32, out, loss_sum, counter, list,
                                             res_v, res_i);
    fin_kernel<<<1, 1, 0, stream>>>(loss_sum, out);
}